// Round 10
// baseline (755.165 us; speedup 1.0000x reference)
//
#include <hip/hip_runtime.h>

#define N_NODES 50000
#define N_EDGES 800000
#define NTB ((N_NODES + 63) / 64)   // 782 node tiles (64 nodes/tile)
#define NPB 256                     // persistent blocks per chunk-x (8*256 = 8 blocks/CU)
// feats: 512 -> 512 -> 512 -> 256; K always 512. Internal dtype: fp16.
// H chunk-blocked [chunk][node][32feats]; 3.2MB/chunk < 4MiB per-XCD L2;
// chunk->XCD pinned via blockIdx.x (proven: FETCH 425->62MB). CSR permuted
// into degree-sorted order (csr2/prow/porder): wave owns 16 consecutive
// sorted nodes w/ contiguous edges -> coalesced per-wave LDS slab + zero-
// shuffle node-slot gather (4 lanes x 16B) + 8-deep named-register batching.
// v7 LESSON: 2 chunks live per XCD = 6.4MB > L2 -> thrash; keep 1 resident.
// v9 (this round): PERSISTENT blocks -- grid (8,256) = exactly 8 blocks/CU;
// block loops phase {x, x+8} then strided sorted tiles; waves free-run (no
// barriers, wave-private slabs). Kills per-block churn (48% occupancy, 9us
// lifetime for ~1.3us work). Pre-commit: <7% gain => L2-request-bound, done.
// Preproc: norm fused into bucket_hist; base2[]=prow[rank[]] kills fill's
// chained random read; rank[] dropped.

typedef __attribute__((ext_vector_type(8))) _Float16 half8;
typedef __attribute__((ext_vector_type(4))) float f32x4;
typedef __attribute__((ext_vector_type(8))) unsigned short ushort8;

// ---------------- fp16 helpers ----------------
static __device__ __forceinline__ unsigned short f2h(float f) {
    _Float16 h = (_Float16)f;   // RNE
    return __builtin_bit_cast(unsigned short, h);
}
static __device__ __forceinline__ float h2f(unsigned short u) {
    return (float)__builtin_bit_cast(_Float16, u);
}

// async global->LDS, 16B per lane (wave-uniform LDS base + lane*16 layout)
static __device__ __forceinline__ void async16(unsigned short* lds, const unsigned short* g) {
    __builtin_amdgcn_global_load_lds(
        (const __attribute__((address_space(1))) void*)g,
        (__attribute__((address_space(3))) void*)lds, 16, 0, 0);
}

// ---------------- int degree histograms ----------------
__global__ void hist_kernel(const int* __restrict__ src, const int* __restrict__ dst,
                            int* __restrict__ outc, int* __restrict__ inc) {
    int i = blockIdx.x * blockDim.x + threadIdx.x;
    if (i < N_EDGES) {
        atomicAdd(&outc[src[i]], 1);
        atomicAdd(&inc[dst[i]], 1);
    }
}

// ---------------- hierarchical exclusive scan (3 kernels) ----------------
__global__ __launch_bounds__(256) void scan1(const int* __restrict__ cnt,
                                             int* __restrict__ row_start,
                                             int* __restrict__ bsum, int n) {
    __shared__ int t[256];
    int tid = threadIdx.x;
    int i = blockIdx.x * 256 + tid;
    int v = (i < n) ? cnt[i] : 0;
    t[tid] = v;
    __syncthreads();
#pragma unroll
    for (int off = 1; off < 256; off <<= 1) {
        int x = (tid >= off) ? t[tid - off] : 0;
        __syncthreads();
        t[tid] += x;
        __syncthreads();
    }
    if (i < n) row_start[i] = t[tid] - v;
    if (tid == 255) bsum[blockIdx.x] = t[255];
}

__global__ __launch_bounds__(256) void scan2(int* __restrict__ bsum,
                                             int* __restrict__ boff,
                                             int* __restrict__ row_start, int nb) {
    __shared__ int t[256];
    int tid = threadIdx.x;
    int v = (tid < nb) ? bsum[tid] : 0;
    t[tid] = v;
    __syncthreads();
#pragma unroll
    for (int off = 1; off < 256; off <<= 1) {
        int x = (tid >= off) ? t[tid - off] : 0;
        __syncthreads();
        t[tid] += x;
        __syncthreads();
    }
    if (tid < nb) boff[tid] = t[tid] - v;
    if (tid == 0) row_start[N_NODES] = N_EDGES;
}

__global__ __launch_bounds__(256) void scan3(int* __restrict__ row_start,
                                             const int* __restrict__ boff, int n) {
    int i = blockIdx.x * 256 + threadIdx.x;
    if (i < n) row_start[i] += boff[blockIdx.x];
}

// ---------------- degree counting sort (LDS-aggregated) + fused norms ----------------
__global__ __launch_bounds__(256) void bucket_hist_norm(
        const int* __restrict__ inc, const int* __restrict__ outc,
        int* __restrict__ bcnt, float* __restrict__ outn, float* __restrict__ inn) {
    __shared__ int lh[1024];
    int tid = threadIdx.x;
    for (int b = tid; b < 1024; b += 256) lh[b] = 0;
    __syncthreads();
    int i = blockIdx.x * 256 + tid;
    if (i < N_NODES) {
        int dc = inc[i];
        atomicAdd(&lh[min(dc, 1023)], 1);
        outn[i] = rsqrtf(fmaxf((float)outc[i], 1.0f));
        inn[i]  = rsqrtf(fmaxf((float)dc, 1.0f));
    }
    __syncthreads();
    for (int b = tid; b < 1024; b += 256) {
        int v = lh[b];
        if (v) atomicAdd(&bcnt[b], v);
    }
}

__global__ __launch_bounds__(1024) void bucket_scan(const int* __restrict__ bcnt,
                                                    int* __restrict__ boff2) {
    __shared__ int t[1024];
    int tid = threadIdx.x;
    int v = bcnt[tid];
    t[tid] = v;
    __syncthreads();
#pragma unroll
    for (int off = 1; off < 1024; off <<= 1) {
        int x = (tid >= off) ? t[tid - off] : 0;
        __syncthreads();
        t[tid] += x;
        __syncthreads();
    }
    boff2[tid] = t[tid] - v;
}

// porder[p]=node, pdeg[p]=deg (degree-sorted order; within-bucket order
// arbitrary). Block-aggregated: LDS atomics give local pos; one global
// atomic per (block, nonzero bucket).
__global__ __launch_bounds__(256) void bucket_scatter(const int* __restrict__ inc,
                               int* __restrict__ bcur,
                               int* __restrict__ porder, int* __restrict__ pdeg) {
    __shared__ int lcnt[1024];
    __shared__ int gbase[1024];
    int tid = threadIdx.x;
    for (int b = tid; b < 1024; b += 256) lcnt[b] = 0;
    __syncthreads();
    int i = blockIdx.x * 256 + tid;
    int deg = 0, bkt = 0, lpos = 0;
    if (i < N_NODES) {
        deg = inc[i];
        bkt = min(deg, 1023);
        lpos = atomicAdd(&lcnt[bkt], 1);
    }
    __syncthreads();
    for (int b = tid; b < 1024; b += 256) {
        int v = lcnt[b];
        if (v) gbase[b] = atomicAdd(&bcur[b], v);
    }
    __syncthreads();
    if (i < N_NODES) {
        int p = gbase[bkt] + lpos;
        porder[p] = i;
        pdeg[p] = deg;
    }
}

// base2[node] = prow[rank[node]] (one random read instead of two chained in fill)
__global__ void write_base2(const int* __restrict__ porder, const int* __restrict__ prow,
                            int* __restrict__ base2) {
    int p = blockIdx.x * blockDim.x + threadIdx.x;
    if (p < N_NODES) base2[porder[p]] = prow[p];
}

// ---------------- CSR fill (directly into degree-sorted layout) ----------------
__global__ void fill_kernel(const int* __restrict__ src, const int* __restrict__ dst,
                            const int* __restrict__ base2,
                            int* __restrict__ cursor, int* __restrict__ csr2) {
    int e = blockIdx.x * blockDim.x + threadIdx.x;
    if (e < N_EDGES) {
        int d = dst[e];
        int pos = atomicAdd(&cursor[d], 1);
        csr2[base2[d] + pos] = src[e];
    }
}

// ---------------- W [K,N] fp32 -> Wt [N,K] fp16 (transpose) ----------------
__global__ __launch_bounds__(256) void conv_W(const float* __restrict__ W,
                                              unsigned short* __restrict__ Wt,
                                              int K, int N) {
    __shared__ float t[32][33];
    int tx = threadIdx.x & 31, ty = threadIdx.x >> 5;   // 32 x 8
    int kb = blockIdx.x * 32, nb = blockIdx.y * 32;
#pragma unroll
    for (int i = 0; i < 4; ++i)
        t[ty + 8 * i][tx] = W[(size_t)(kb + ty + 8 * i) * N + nb + tx];
    __syncthreads();
#pragma unroll
    for (int i = 0; i < 4; ++i) {
        float v = t[tx][ty + 8 * i];
        int n = nb + ty + 8 * i, k = kb + tx;
        Wt[(size_t)n * K + k] = f2h(v);
    }
}

// ---------------- feat [M,512] fp32 -> (outn[row]*feat) fp16 ----------------
__global__ void conv_A(const float4* __restrict__ feat4, const float* __restrict__ outn,
                       ushort4* __restrict__ Af, long total4) {
    long i = (long)blockIdx.x * blockDim.x + threadIdx.x;
    if (i >= total4) return;
    int row = (int)(i >> 7);            // 512/4 = 128 float4 per row
    float s = outn[row];
    float4 v = feat4[i];
    ushort4 h;
    h.x = f2h(v.x * s);
    h.y = f2h(v.y * s);
    h.z = f2h(v.z * s);
    h.w = f2h(v.w * s);
    Af[i] = h;
}

// ---------------- MFMA GEMM: C = A @ B^T, fp16 in/out, fp32 acc, K=512 ----------------
// 128x128 tile, BK=32, 256 threads = 4 waves; global_load_lds (16B) staging.
// Output C is written in CHUNK-BLOCKED layout: C[((col>>5)*M + row)*32 + (col&31)].
__global__ __launch_bounds__(256) void gemm_mfma(
    const unsigned short* __restrict__ A, const unsigned short* __restrict__ B,
    unsigned short* __restrict__ C, int M, int N)
{
    const int K = 512;
    __shared__ unsigned short sA[128 * 32];
    __shared__ unsigned short sB[128 * 32];

    const int tid = threadIdx.x;
    const int rowBase = blockIdx.x * 128;
    const int colBase = blockIdx.y * 128;
    const int wave = tid >> 6;
    const int lane = tid & 63;
    const int wr = (wave >> 1) * 64;
    const int wc = (wave & 1) * 64;
    const int lrow = lane & 15;
    const int quad = lane >> 4;

    f32x4 acc[4][4] = {};

    // staging: thread tid -> row tid>>2 (and +64), k-chunk (tid&3)*8; LDS dest = tid*16 B
    const int crow = tid >> 2;
    const int ck   = (tid & 3) * 8;
    const int ar0 = min(rowBase + crow, M - 1);
    const int ar1 = min(rowBase + 64 + crow, M - 1);
    const int bn0 = colBase + crow;
    const int bn1 = colBase + 64 + crow;
    const int ldsOf0 = tid * 8;          // ushort units
    const int ldsOf1 = 64 * 32 + tid * 8;

    for (int k0 = 0; k0 < K; k0 += 32) {
        __syncthreads();   // previous tile's compute done before overwrite
        async16(sA + ldsOf0, A + (size_t)ar0 * K + k0 + ck);
        async16(sA + ldsOf1, A + (size_t)ar1 * K + k0 + ck);
        async16(sB + ldsOf0, B + (size_t)bn0 * K + k0 + ck);
        async16(sB + ldsOf1, B + (size_t)bn1 * K + k0 + ck);
        __syncthreads();   // drains vmcnt (global_load_lds) + barrier

        half8 av[4], bv[4];
#pragma unroll
        for (int mt = 0; mt < 4; ++mt)
            av[mt] = *(const half8*)&sA[(wr + mt * 16 + lrow) * 32 + quad * 8];
#pragma unroll
        for (int nt = 0; nt < 4; ++nt)
            bv[nt] = *(const half8*)&sB[(wc + nt * 16 + lrow) * 32 + quad * 8];
#pragma unroll
        for (int mt = 0; mt < 4; ++mt)
#pragma unroll
            for (int nt = 0; nt < 4; ++nt)
                acc[mt][nt] = __builtin_amdgcn_mfma_f32_16x16x32_f16(av[mt], bv[nt], acc[mt][nt], 0, 0, 0);
    }

    // epilogue: C/D layout col=lane&15, row=quad*4+reg; store fp16, chunk-blocked.
#pragma unroll
    for (int mt = 0; mt < 4; ++mt) {
        int grow0 = rowBase + wr + mt * 16 + quad * 4;
#pragma unroll
        for (int nt = 0; nt < 4; ++nt) {
            int gcol = colBase + wc + nt * 16 + lrow;
            size_t chunkBase = (size_t)(gcol >> 5) * M * 32 + (gcol & 31);
#pragma unroll
            for (int r = 0; r < 4; ++r) {
                int grow = grow0 + r;
                if (grow < M) C[chunkBase + (size_t)grow * 32] = f2h(acc[mt][nt][r]);
            }
        }
    }
}

// ---------------- persistent chunked gather-aggregate v9 ----------------
#define SLAB 1024

#define GATHER8(ACC, HSRC, K0)                                                  \
    {                                                                           \
        int i0 = slab[(K0) + 0], i1 = slab[(K0) + 1];                           \
        int i2 = slab[(K0) + 2], i3 = slab[(K0) + 3];                           \
        int i4 = slab[(K0) + 4], i5 = slab[(K0) + 5];                           \
        int i6 = slab[(K0) + 6], i7 = slab[(K0) + 7];                           \
        const ushort8 u0 = *(const ushort8*)(HSRC + (unsigned)i0 * 32u + fo);   \
        const ushort8 u1 = *(const ushort8*)(HSRC + (unsigned)i1 * 32u + fo);   \
        const ushort8 u2 = *(const ushort8*)(HSRC + (unsigned)i2 * 32u + fo);   \
        const ushort8 u3 = *(const ushort8*)(HSRC + (unsigned)i3 * 32u + fo);   \
        const ushort8 u4 = *(const ushort8*)(HSRC + (unsigned)i4 * 32u + fo);   \
        const ushort8 u5 = *(const ushort8*)(HSRC + (unsigned)i5 * 32u + fo);   \
        const ushort8 u6 = *(const ushort8*)(HSRC + (unsigned)i6 * 32u + fo);   \
        const ushort8 u7 = *(const ushort8*)(HSRC + (unsigned)i7 * 32u + fo);   \
        _Pragma("unroll")                                                       \
        for (int q = 0; q < 8; ++q) {                                           \
            ACC[q] += h2f(u0[q]); ACC[q] += h2f(u1[q]);                         \
            ACC[q] += h2f(u2[q]); ACC[q] += h2f(u3[q]);                         \
            ACC[q] += h2f(u4[q]); ACC[q] += h2f(u5[q]);                         \
            ACC[q] += h2f(u6[q]); ACC[q] += h2f(u7[q]);                         \
        }                                                                       \
    }

#define GATHER1(ACC, HSRC, K0)                                                  \
    {                                                                           \
        int idx = slab[(K0)];                                                   \
        const ushort8 u = *(const ushort8*)(HSRC + (unsigned)idx * 32u + fo);   \
        _Pragma("unroll")                                                       \
        for (int q = 0; q < 8; ++q) ACC[q] += h2f(u[q]);                        \
    }

// grid (8, NPB). Block persists; loops phase {x, x+8} then tiles
// j = y, y+NPB, ... mapped to ty = NTB-1-j (heavy first; lightest 14 tiles
// are the remainder work). Waves free-run (wave-private slabs, no barriers).
__global__ __launch_bounds__(256) void agg_f16_v9(
    const unsigned short* __restrict__ H, const int* __restrict__ csr2,
    const int* __restrict__ porder, const int* __restrict__ prow,
    const float* __restrict__ inn, const float* __restrict__ outn,
    const float* __restrict__ bias, unsigned short* __restrict__ Af)
{
    __shared__ int sIdx[4][SLAB];
    const int tid = threadIdx.x, lane = tid & 63, w = tid >> 6;
    const int s = lane >> 2, f = lane & 3;
    const unsigned fo = (unsigned)f * 8u;
    const int x = blockIdx.x;
    int* slab = sIdx[w];

    for (int phase = 0; phase < 2; ++phase) {
        const int c = phase * 8 + x;
        const unsigned short* Hc = H + (size_t)c * (N_NODES * 32);
        const float4 bq0 = *(const float4*)(bias + c * 32 + f * 8);
        const float4 bq1 = *(const float4*)(bias + c * 32 + f * 8 + 4);

        for (int j = blockIdx.y; j < NTB; j += NPB) {
            const int ty = NTB - 1 - j;              // heavy tiles first
            const int t = ty * 64 + w * 16 + s;
            int d = 0, st = N_EDGES, en = N_EDGES;
            if (t < N_NODES) {                       // waves are fully valid or
                d  = porder[t];                      // fully invalid (50000%64==16)
                st = prow[t];
                en = prow[t + 1];
            }
            const int eStart = __shfl(st, 0);        // slot 0 start
            const int eEnd   = __shfl(en, 63);       // slot 15 end

            float a[8] = {};
            for (int b = eStart; b < eEnd; b += SLAB) {
                const int nstage = min(eEnd - b, SLAB);
                for (int i = lane; i < nstage; i += 64)
                    slab[i] = __builtin_nontemporal_load(csr2 + b + i);
                asm volatile("s_waitcnt lgkmcnt(0)" ::: "memory");

                const int js = max(st, b);
                const int je = min(en, b + nstage);
                int k = js;
                for (; k + 8 <= je; k += 8) GATHER8(a, Hc, k - b);
                for (; k < je; ++k) GATHER1(a, Hc, k - b);
                asm volatile("" ::: "memory");       // reads before overwrite
            }

            if (t < N_NODES) {
                float si = inn[d], so = outn[d];
                ushort8 h;
                h[0] = f2h(fmaxf(a[0] * si + bq0.x, 0.f) * so);
                h[1] = f2h(fmaxf(a[1] * si + bq0.y, 0.f) * so);
                h[2] = f2h(fmaxf(a[2] * si + bq0.z, 0.f) * so);
                h[3] = f2h(fmaxf(a[3] * si + bq0.w, 0.f) * so);
                h[4] = f2h(fmaxf(a[4] * si + bq1.x, 0.f) * so);
                h[5] = f2h(fmaxf(a[5] * si + bq1.y, 0.f) * so);
                h[6] = f2h(fmaxf(a[6] * si + bq1.z, 0.f) * so);
                h[7] = f2h(fmaxf(a[7] * si + bq1.w, 0.f) * so);
                __builtin_nontemporal_store(h,
                    (ushort8*)(Af + (size_t)d * 512 + c * 32 + f * 8));
            }
        }
    }
}

// ---------------- persistent final aggregate v9: fp32 out, no relu ----------------
__global__ __launch_bounds__(256) void agg_f32_v9(
    const unsigned short* __restrict__ H, const int* __restrict__ csr2,
    const int* __restrict__ porder, const int* __restrict__ prow,
    const float* __restrict__ inn, const float* __restrict__ bias,
    float* __restrict__ out)
{
    __shared__ int sIdx[4][SLAB];
    const int tid = threadIdx.x, lane = tid & 63, w = tid >> 6;
    const int s = lane >> 2, f = lane & 3;
    const unsigned fo = (unsigned)f * 8u;
    const int c = blockIdx.x;                        // chunk 0..7
    int* slab = sIdx[w];

    const unsigned short* Hc = H + (size_t)c * (N_NODES * 32);
    const float4 bq0 = *(const float4*)(bias + c * 32 + f * 8);
    const float4 bq1 = *(const float4*)(bias + c * 32 + f * 8 + 4);

    for (int j = blockIdx.y; j < NTB; j += NPB) {
        const int ty = NTB - 1 - j;
        const int t = ty * 64 + w * 16 + s;
        int d = 0, st = N_EDGES, en = N_EDGES;
        if (t < N_NODES) {
            d  = porder[t];
            st = prow[t];
            en = prow[t + 1];
        }
        const int eStart = __shfl(st, 0);
        const int eEnd   = __shfl(en, 63);

        float a[8] = {};
        for (int b = eStart; b < eEnd; b += SLAB) {
            const int nstage = min(eEnd - b, SLAB);
            for (int i = lane; i < nstage; i += 64)
                slab[i] = __builtin_nontemporal_load(csr2 + b + i);
            asm volatile("s_waitcnt lgkmcnt(0)" ::: "memory");

            const int js = max(st, b);
            const int je = min(en, b + nstage);
            int k = js;
            for (; k + 8 <= je; k += 8) GATHER8(a, Hc, k - b);
            for (; k < je; ++k) GATHER1(a, Hc, k - b);
            asm volatile("" ::: "memory");
        }

        if (t < N_NODES) {
            float si = inn[d];
            f32x4 r0, r1;
            r0.x = a[0] * si + bq0.x; r0.y = a[1] * si + bq0.y;
            r0.z = a[2] * si + bq0.z; r0.w = a[3] * si + bq0.w;
            r1.x = a[4] * si + bq1.x; r1.y = a[5] * si + bq1.y;
            r1.z = a[6] * si + bq1.z; r1.w = a[7] * si + bq1.w;
            float* op = out + (size_t)d * 256 + c * 32 + f * 8;
            __builtin_nontemporal_store(r0, (f32x4*)op);
            __builtin_nontemporal_store(r1, (f32x4*)(op + 4));
        }
    }
}

extern "C" void kernel_launch(void* const* d_in, const int* in_sizes, int n_in,
                              void* d_out, int out_size, void* d_ws, size_t ws_size,
                              hipStream_t stream) {
    const float* feat = (const float*)d_in[0];
    const int*   src  = (const int*)d_in[1];
    const int*   dst  = (const int*)d_in[2];
    const float* W0   = (const float*)d_in[3];
    const float* b0   = (const float*)d_in[4];
    const float* W1   = (const float*)d_in[5];
    const float* b1   = (const float*)d_in[6];
    const float* W2   = (const float*)d_in[7];
    const float* b2   = (const float*)d_in[8];
    float* out = (float*)d_out;

    // ---- workspace bump allocator (64B aligned) ----
    char* p = (char*)d_ws;
    auto alloc = [&](size_t bytes) {
        char* r = p;
        p += (bytes + 63) & ~(size_t)63;
        return r;
    };
    float* outn = (float*)alloc(N_NODES * 4);
    float* inn  = (float*)alloc(N_NODES * 4);
    int* outc      = (int*)alloc(N_NODES * 4);     // | contiguous zero block:
    int* inc       = (int*)alloc(N_NODES * 4);     // | outc, inc, cursor, bcnt
    int* cursor    = (int*)alloc(N_NODES * 4);     // | (N_NODES*4 is 64B-mult)
    int* bcnt      = (int*)alloc(1024 * 4);        // |
    int* porder    = (int*)alloc(N_NODES * 4);
    int* pdeg      = (int*)alloc(N_NODES * 4);
    int* base2     = (int*)alloc(N_NODES * 4);
    int* prow      = (int*)alloc((N_NODES + 1) * 4);
    int* bsum      = (int*)alloc(256 * 4);
    int* boff      = (int*)alloc(256 * 4);
    int* boff2     = (int*)alloc(1024 * 4);
    int* csr2      = (int*)alloc(N_EDGES * 4);
    unsigned short* W0t = (unsigned short*)alloc(512 * 512 * 2);
    unsigned short* W1t = (unsigned short*)alloc(512 * 512 * 2);
    unsigned short* W2t = (unsigned short*)alloc(256 * 512 * 2);
    unsigned short* Af  = (unsigned short*)alloc((size_t)N_NODES * 512 * 2);
    unsigned short* H   = (unsigned short*)alloc((size_t)N_NODES * 512 * 2);

    const int NB = (N_NODES + 255) / 256;   // 196

    // ---- degrees + norms + degree sort + sorted CSR ----
    hipMemsetAsync(outc, 0, (size_t)3 * N_NODES * 4 + 1024 * 4, stream);
    hist_kernel<<<(N_EDGES + 255) / 256, 256, 0, stream>>>(src, dst, outc, inc);
    bucket_hist_norm<<<NB, 256, 0, stream>>>(inc, outc, bcnt, outn, inn);
    bucket_scan<<<1, 1024, 0, stream>>>(bcnt, boff2);
    bucket_scatter<<<NB, 256, 0, stream>>>(inc, boff2, porder, pdeg);
    scan1<<<NB, 256, 0, stream>>>(pdeg, prow, bsum, N_NODES);
    scan2<<<1, 256, 0, stream>>>(bsum, boff, prow, NB);
    scan3<<<NB, 256, 0, stream>>>(prow, boff, N_NODES);
    write_base2<<<NB, 256, 0, stream>>>(porder, prow, base2);
    fill_kernel<<<(N_EDGES + 255) / 256, 256, 0, stream>>>(src, dst, base2, cursor, csr2);

    // ---- weight transpose to fp16 ----
    conv_W<<<dim3(16, 16), 256, 0, stream>>>(W0, W0t, 512, 512);
    conv_W<<<dim3(16, 16), 256, 0, stream>>>(W1, W1t, 512, 512);
    conv_W<<<dim3(16, 8),  256, 0, stream>>>(W2, W2t, 512, 256);

    // ---- feature scale to fp16 ----
    long total4 = (long)N_NODES * 128;
    conv_A<<<(int)((total4 + 255) / 256), 256, 0, stream>>>(
        (const float4*)feat, outn, (ushort4*)Af, total4);

    dim3 g512((N_NODES + 127) / 128, 4);
    dim3 g256((N_NODES + 127) / 128, 2);
    dim3 gAgg(8, NPB);                      // persistent: 8 blocks/CU exactly

    // ---- layer 0 ----
    gemm_mfma<<<g512, 256, 0, stream>>>(Af, W0t, H, N_NODES, 512);
    agg_f16_v9<<<gAgg, 256, 0, stream>>>(
        H, csr2, porder, prow, inn, outn, b0, Af);

    // ---- layer 1 ----
    gemm_mfma<<<g512, 256, 0, stream>>>(Af, W1t, H, N_NODES, 512);
    agg_f16_v9<<<gAgg, 256, 0, stream>>>(
        H, csr2, porder, prow, inn, outn, b1, Af);

    // ---- layer 2 (256 out, no relu, fp32) ----
    gemm_mfma<<<g256, 256, 0, stream>>>(Af, W2t, H, N_NODES, 256);
    agg_f32_v9<<<gAgg, 256, 0, stream>>>(
        H, csr2, porder, prow, inn, b2, out);
}

// Round 11
// 718.304 us; speedup vs baseline: 1.0513x; 1.0513x over previous
//
#include <hip/hip_runtime.h>

#define N_NODES 50000
#define N_EDGES 800000
#define NTB ((N_NODES + 63) / 64)   // 782 node tiles (64 nodes/tile)
// feats: 512 -> 512 -> 512 -> 256; K always 512. Internal dtype: fp16.
// H chunk-blocked [chunk][node][32feats]; 3.2MB/chunk < 4MiB per-XCD L2;
// chunk->XCD pinned via blockIdx.x (proven: FETCH 425->62MB). CSR permuted
// into degree-sorted order (csr2/prow/porder): wave owns 16 consecutive
// sorted nodes w/ contiguous edges -> coalesced per-wave LDS slab + zero-
// shuffle node-slot gather (4 lanes x 16B) + 8-deep named-register batching.
// LESSONS: v7 two-chunks-live = L2 thrash; v9 persistent blocks reintroduced
// it (phase skew) + static imbalance -> REVERTED to v8 agg (115us proven).
// v10 (this round): closed-form counting sort -- bucket b = nodes with
// deg==b exactly, so edge offsets escan[b] = scan(b*bcnt[b]) and
// prow[p] = escan[b] + (p-nscan[b])*deg come straight out of scatter.
// Deletes scan1/scan2/scan3/write_base2 (4 dispatches); conv_W fused to one.

typedef __attribute__((ext_vector_type(8))) _Float16 half8;
typedef __attribute__((ext_vector_type(4))) float f32x4;
typedef __attribute__((ext_vector_type(8))) unsigned short ushort8;

// ---------------- fp16 helpers ----------------
static __device__ __forceinline__ unsigned short f2h(float f) {
    _Float16 h = (_Float16)f;   // RNE
    return __builtin_bit_cast(unsigned short, h);
}
static __device__ __forceinline__ float h2f(unsigned short u) {
    return (float)__builtin_bit_cast(_Float16, u);
}

// async global->LDS, 16B per lane (wave-uniform LDS base + lane*16 layout)
static __device__ __forceinline__ void async16(unsigned short* lds, const unsigned short* g) {
    __builtin_amdgcn_global_load_lds(
        (const __attribute__((address_space(1))) void*)g,
        (__attribute__((address_space(3))) void*)lds, 16, 0, 0);
}

// ---------------- int degree histograms ----------------
__global__ void hist_kernel(const int* __restrict__ src, const int* __restrict__ dst,
                            int* __restrict__ outc, int* __restrict__ inc) {
    int i = blockIdx.x * blockDim.x + threadIdx.x;
    if (i < N_EDGES) {
        atomicAdd(&outc[src[i]], 1);
        atomicAdd(&inc[dst[i]], 1);
    }
}

// ---------------- degree counting sort (LDS-aggregated) + fused norms ----------------
__global__ __launch_bounds__(256) void bucket_hist_norm(
        const int* __restrict__ inc, const int* __restrict__ outc,
        int* __restrict__ bcnt, float* __restrict__ outn, float* __restrict__ inn) {
    __shared__ int lh[1024];
    int tid = threadIdx.x;
    for (int b = tid; b < 1024; b += 256) lh[b] = 0;
    __syncthreads();
    int i = blockIdx.x * 256 + tid;
    if (i < N_NODES) {
        int dc = inc[i];
        atomicAdd(&lh[min(dc, 1023)], 1);
        outn[i] = rsqrtf(fmaxf((float)outc[i], 1.0f));
        inn[i]  = rsqrtf(fmaxf((float)dc, 1.0f));
    }
    __syncthreads();
    for (int b = tid; b < 1024; b += 256) {
        int v = lh[b];
        if (v) atomicAdd(&bcnt[b], v);
    }
}

// Dual exclusive scan over buckets: node offsets nscan (-> bcur working copy
// + immutable n0) and edge offsets escan[b] = scan of b*bcnt[b] (-> e0).
// Valid because bucket b contains exactly the deg==b nodes (max deg << 1023).
// Also seeds prow[N_NODES] = N_EDGES.
__global__ __launch_bounds__(1024) void bucket_scan(const int* __restrict__ bcnt,
                                                    int* __restrict__ bcur,
                                                    int* __restrict__ n0,
                                                    int* __restrict__ e0,
                                                    int* __restrict__ prow) {
    __shared__ int t[1024];
    __shared__ int u[1024];
    int tid = threadIdx.x;
    int v = bcnt[tid];
    int w = v * tid;                 // edges contributed by bucket tid
    t[tid] = v;
    u[tid] = w;
    __syncthreads();
#pragma unroll
    for (int off = 1; off < 1024; off <<= 1) {
        int x = (tid >= off) ? t[tid - off] : 0;
        int y = (tid >= off) ? u[tid - off] : 0;
        __syncthreads();
        t[tid] += x;
        u[tid] += y;
        __syncthreads();
    }
    bcur[tid] = t[tid] - v;
    n0[tid]   = t[tid] - v;
    e0[tid]   = u[tid] - w;
    if (tid == 0) prow[N_NODES] = N_EDGES;
}

// porder[p]=node; prow[p] = closed-form edge start; base2[node] = prow[p].
// Block-aggregated: LDS atomics give local pos; one global atomic per
// (block, nonzero bucket). Within-bucket order arbitrary (grouping suffices).
__global__ __launch_bounds__(256) void bucket_scatter(const int* __restrict__ inc,
                               int* __restrict__ bcur,
                               const int* __restrict__ n0, const int* __restrict__ e0,
                               int* __restrict__ porder, int* __restrict__ prow,
                               int* __restrict__ base2) {
    __shared__ int lcnt[1024];
    __shared__ int gbase[1024];
    int tid = threadIdx.x;
    for (int b = tid; b < 1024; b += 256) lcnt[b] = 0;
    __syncthreads();
    int i = blockIdx.x * 256 + tid;
    int deg = 0, bkt = 0, lpos = 0;
    if (i < N_NODES) {
        deg = inc[i];
        bkt = min(deg, 1023);
        lpos = atomicAdd(&lcnt[bkt], 1);
    }
    __syncthreads();
    for (int b = tid; b < 1024; b += 256) {
        int v = lcnt[b];
        if (v) gbase[b] = atomicAdd(&bcur[b], v);
    }
    __syncthreads();
    if (i < N_NODES) {
        int p = gbase[bkt] + lpos;
        int rs = e0[bkt] + (p - n0[bkt]) * deg;
        porder[p] = i;
        prow[p] = rs;
        base2[i] = rs;
    }
}

// ---------------- CSR fill (directly into degree-sorted layout) ----------------
__global__ void fill_kernel(const int* __restrict__ src, const int* __restrict__ dst,
                            const int* __restrict__ base2,
                            int* __restrict__ cursor, int* __restrict__ csr2) {
    int e = blockIdx.x * blockDim.x + threadIdx.x;
    if (e < N_EDGES) {
        int d = dst[e];
        int pos = atomicAdd(&cursor[d], 1);
        csr2[base2[d] + pos] = src[e];
    }
}

// ---------------- W [K,N] fp32 -> Wt [N,K] fp16, all 3 layers in one launch ----------------
__global__ __launch_bounds__(256) void conv_W3(
        const float* __restrict__ W0, const float* __restrict__ W1,
        const float* __restrict__ W2, unsigned short* __restrict__ Wt0,
        unsigned short* __restrict__ Wt1, unsigned short* __restrict__ Wt2) {
    const int l = blockIdx.z;
    const float* W = (l == 0) ? W0 : (l == 1) ? W1 : W2;
    unsigned short* Wt = (l == 0) ? Wt0 : (l == 1) ? Wt1 : Wt2;
    const int K = 512;
    const int N = (l == 2) ? 256 : 512;
    int nb = blockIdx.y * 32;
    if (nb >= N) return;
    __shared__ float t[32][33];
    int tx = threadIdx.x & 31, ty = threadIdx.x >> 5;   // 32 x 8
    int kb = blockIdx.x * 32;
#pragma unroll
    for (int i = 0; i < 4; ++i)
        t[ty + 8 * i][tx] = W[(size_t)(kb + ty + 8 * i) * N + nb + tx];
    __syncthreads();
#pragma unroll
    for (int i = 0; i < 4; ++i) {
        float v = t[tx][ty + 8 * i];
        int n = nb + ty + 8 * i, k = kb + tx;
        Wt[(size_t)n * K + k] = f2h(v);
    }
}

// ---------------- feat [M,512] fp32 -> (outn[row]*feat) fp16 ----------------
__global__ void conv_A(const float4* __restrict__ feat4, const float* __restrict__ outn,
                       ushort4* __restrict__ Af, long total4) {
    long i = (long)blockIdx.x * blockDim.x + threadIdx.x;
    if (i >= total4) return;
    int row = (int)(i >> 7);            // 512/4 = 128 float4 per row
    float s = outn[row];
    float4 v = feat4[i];
    ushort4 h;
    h.x = f2h(v.x * s);
    h.y = f2h(v.y * s);
    h.z = f2h(v.z * s);
    h.w = f2h(v.w * s);
    Af[i] = h;
}

// ---------------- MFMA GEMM: C = A @ B^T, fp16 in/out, fp32 acc, K=512 ----------------
// 128x128 tile, BK=32, 256 threads = 4 waves; global_load_lds (16B) staging.
// Output C is written in CHUNK-BLOCKED layout: C[((col>>5)*M + row)*32 + (col&31)].
__global__ __launch_bounds__(256) void gemm_mfma(
    const unsigned short* __restrict__ A, const unsigned short* __restrict__ B,
    unsigned short* __restrict__ C, int M, int N)
{
    const int K = 512;
    __shared__ unsigned short sA[128 * 32];
    __shared__ unsigned short sB[128 * 32];

    const int tid = threadIdx.x;
    const int rowBase = blockIdx.x * 128;
    const int colBase = blockIdx.y * 128;
    const int wave = tid >> 6;
    const int lane = tid & 63;
    const int wr = (wave >> 1) * 64;
    const int wc = (wave & 1) * 64;
    const int lrow = lane & 15;
    const int quad = lane >> 4;

    f32x4 acc[4][4] = {};

    // staging: thread tid -> row tid>>2 (and +64), k-chunk (tid&3)*8; LDS dest = tid*16 B
    const int crow = tid >> 2;
    const int ck   = (tid & 3) * 8;
    const int ar0 = min(rowBase + crow, M - 1);
    const int ar1 = min(rowBase + 64 + crow, M - 1);
    const int bn0 = colBase + crow;
    const int bn1 = colBase + 64 + crow;
    const int ldsOf0 = tid * 8;          // ushort units
    const int ldsOf1 = 64 * 32 + tid * 8;

    for (int k0 = 0; k0 < K; k0 += 32) {
        __syncthreads();   // previous tile's compute done before overwrite
        async16(sA + ldsOf0, A + (size_t)ar0 * K + k0 + ck);
        async16(sA + ldsOf1, A + (size_t)ar1 * K + k0 + ck);
        async16(sB + ldsOf0, B + (size_t)bn0 * K + k0 + ck);
        async16(sB + ldsOf1, B + (size_t)bn1 * K + k0 + ck);
        __syncthreads();   // drains vmcnt (global_load_lds) + barrier

        half8 av[4], bv[4];
#pragma unroll
        for (int mt = 0; mt < 4; ++mt)
            av[mt] = *(const half8*)&sA[(wr + mt * 16 + lrow) * 32 + quad * 8];
#pragma unroll
        for (int nt = 0; nt < 4; ++nt)
            bv[nt] = *(const half8*)&sB[(wc + nt * 16 + lrow) * 32 + quad * 8];
#pragma unroll
        for (int mt = 0; mt < 4; ++mt)
#pragma unroll
            for (int nt = 0; nt < 4; ++nt)
                acc[mt][nt] = __builtin_amdgcn_mfma_f32_16x16x32_f16(av[mt], bv[nt], acc[mt][nt], 0, 0, 0);
    }

    // epilogue: C/D layout col=lane&15, row=quad*4+reg; store fp16, chunk-blocked.
#pragma unroll
    for (int mt = 0; mt < 4; ++mt) {
        int grow0 = rowBase + wr + mt * 16 + quad * 4;
#pragma unroll
        for (int nt = 0; nt < 4; ++nt) {
            int gcol = colBase + wc + nt * 16 + lrow;
            size_t chunkBase = (size_t)(gcol >> 5) * M * 32 + (gcol & 31);
#pragma unroll
            for (int r = 0; r < 4; ++r) {
                int grow = grow0 + r;
                if (grow < M) C[chunkBase + (size_t)grow * 32] = f2h(acc[mt][nt][r]);
            }
        }
    }
}

// ---------------- chunked gather-aggregate v8 (single chunk + LPT) ----------------
// grid (8, NTB, 2). chunk c = z*8+x -> XCD x (3.2MB resident -- the proven
// config). LPT: heavy tiles first via ty = gridDim.y-1-y. Block = 4 waves;
// wave owns 16 consecutive sorted nodes w/ contiguous edges in csr2. Slab
// staged coalesced (wave-private, nt, no barriers). Lane = (slot s, f);
// 8-deep named-register gathers; per-lane accum, zero-shuffle epilogue.
#define SLAB 1024

#define GATHER8(ACC, HSRC, K0)                                                  \
    {                                                                           \
        int i0 = slab[(K0) + 0], i1 = slab[(K0) + 1];                           \
        int i2 = slab[(K0) + 2], i3 = slab[(K0) + 3];                           \
        int i4 = slab[(K0) + 4], i5 = slab[(K0) + 5];                           \
        int i6 = slab[(K0) + 6], i7 = slab[(K0) + 7];                           \
        const ushort8 u0 = *(const ushort8*)(HSRC + (unsigned)i0 * 32u + fo);   \
        const ushort8 u1 = *(const ushort8*)(HSRC + (unsigned)i1 * 32u + fo);   \
        const ushort8 u2 = *(const ushort8*)(HSRC + (unsigned)i2 * 32u + fo);   \
        const ushort8 u3 = *(const ushort8*)(HSRC + (unsigned)i3 * 32u + fo);   \
        const ushort8 u4 = *(const ushort8*)(HSRC + (unsigned)i4 * 32u + fo);   \
        const ushort8 u5 = *(const ushort8*)(HSRC + (unsigned)i5 * 32u + fo);   \
        const ushort8 u6 = *(const ushort8*)(HSRC + (unsigned)i6 * 32u + fo);   \
        const ushort8 u7 = *(const ushort8*)(HSRC + (unsigned)i7 * 32u + fo);   \
        _Pragma("unroll")                                                       \
        for (int q = 0; q < 8; ++q) {                                           \
            ACC[q] += h2f(u0[q]); ACC[q] += h2f(u1[q]);                         \
            ACC[q] += h2f(u2[q]); ACC[q] += h2f(u3[q]);                         \
            ACC[q] += h2f(u4[q]); ACC[q] += h2f(u5[q]);                         \
            ACC[q] += h2f(u6[q]); ACC[q] += h2f(u7[q]);                         \
        }                                                                       \
    }

#define GATHER1(ACC, HSRC, K0)                                                  \
    {                                                                           \
        int idx = slab[(K0)];                                                   \
        const ushort8 u = *(const ushort8*)(HSRC + (unsigned)idx * 32u + fo);   \
        _Pragma("unroll")                                                       \
        for (int q = 0; q < 8; ++q) ACC[q] += h2f(u[q]);                        \
    }

__global__ __launch_bounds__(256) void agg_f16_v8(
    const unsigned short* __restrict__ H, const int* __restrict__ csr2,
    const int* __restrict__ porder, const int* __restrict__ prow,
    const float* __restrict__ inn, const float* __restrict__ outn,
    const float* __restrict__ bias, unsigned short* __restrict__ Af)
{
    __shared__ int sIdx[4][SLAB];
    const int tid = threadIdx.x, lane = tid & 63, w = tid >> 6;
    const int s = lane >> 2, f = lane & 3;
    const unsigned fo = (unsigned)f * 8u;
    const int c = blockIdx.z * 8 + blockIdx.x;
    const int ty = (int)gridDim.y - 1 - (int)blockIdx.y;   // LPT: heavy first
    const int t = ty * 64 + w * 16 + s;

    int d = 0, st = N_EDGES, en = N_EDGES;
    if (t < N_NODES) {
        d  = porder[t];
        st = prow[t];
        en = prow[t + 1];
    }
    const int eStart = __shfl(st, 0);    // slot 0's start (wave-uniform)
    const int eEnd   = __shfl(en, 63);   // slot 15's end

    const unsigned short* Hc = H + (size_t)c * (N_NODES * 32);
    int* slab = sIdx[w];
    float a[8] = {};

    for (int b = eStart; b < eEnd; b += SLAB) {
        const int nstage = min(eEnd - b, SLAB);
        for (int i = lane; i < nstage; i += 64)
            slab[i] = __builtin_nontemporal_load(csr2 + b + i);
        asm volatile("s_waitcnt lgkmcnt(0)" ::: "memory");

        const int js = max(st, b);
        const int je = min(en, b + nstage);
        int k = js;
        for (; k + 8 <= je; k += 8) GATHER8(a, Hc, k - b);
        for (; k < je; ++k) GATHER1(a, Hc, k - b);
        asm volatile("" ::: "memory");   // reads done before next batch overwrites
    }

    if (t < N_NODES) {
        float si = inn[d], so = outn[d];
        float b8[8];
        *(float4*)&b8[0] = *(const float4*)(bias + c * 32 + f * 8);
        *(float4*)&b8[4] = *(const float4*)(bias + c * 32 + f * 8 + 4);
        ushort8 h;
#pragma unroll
        for (int q = 0; q < 8; ++q)
            h[q] = f2h(fmaxf(a[q] * si + b8[q], 0.f) * so);
        __builtin_nontemporal_store(h,
            (ushort8*)(Af + (size_t)d * 512 + c * 32 + f * 8));
    }
}

// ---------------- final chunked aggregate v8: fp32 out, no relu ----------------
__global__ __launch_bounds__(256) void agg_f32_v8(
    const unsigned short* __restrict__ H, const int* __restrict__ csr2,
    const int* __restrict__ porder, const int* __restrict__ prow,
    const float* __restrict__ inn, const float* __restrict__ bias,
    float* __restrict__ out)
{
    __shared__ int sIdx[4][SLAB];
    const int tid = threadIdx.x, lane = tid & 63, w = tid >> 6;
    const int s = lane >> 2, f = lane & 3;
    const unsigned fo = (unsigned)f * 8u;
    const int c = blockIdx.x;            // chunk 0..7
    const int ty = (int)gridDim.y - 1 - (int)blockIdx.y;   // LPT
    const int t = ty * 64 + w * 16 + s;

    int d = 0, st = N_EDGES, en = N_EDGES;
    if (t < N_NODES) {
        d  = porder[t];
        st = prow[t];
        en = prow[t + 1];
    }
    const int eStart = __shfl(st, 0);
    const int eEnd   = __shfl(en, 63);

    const unsigned short* Hc = H + (size_t)c * (N_NODES * 32);
    int* slab = sIdx[w];
    float a[8] = {};

    for (int b = eStart; b < eEnd; b += SLAB) {
        const int nstage = min(eEnd - b, SLAB);
        for (int i = lane; i < nstage; i += 64)
            slab[i] = __builtin_nontemporal_load(csr2 + b + i);
        asm volatile("s_waitcnt lgkmcnt(0)" ::: "memory");

        const int js = max(st, b);
        const int je = min(en, b + nstage);
        int k = js;
        for (; k + 8 <= je; k += 8) GATHER8(a, Hc, k - b);
        for (; k < je; ++k) GATHER1(a, Hc, k - b);
        asm volatile("" ::: "memory");
    }

    if (t < N_NODES) {
        float si = inn[d];
        float b8[8];
        *(float4*)&b8[0] = *(const float4*)(bias + c * 32 + f * 8);
        *(float4*)&b8[4] = *(const float4*)(bias + c * 32 + f * 8 + 4);
        f32x4 r0, r1;
        r0.x = a[0] * si + b8[0]; r0.y = a[1] * si + b8[1];
        r0.z = a[2] * si + b8[2]; r0.w = a[3] * si + b8[3];
        r1.x = a[4] * si + b8[4]; r1.y = a[5] * si + b8[5];
        r1.z = a[6] * si + b8[6]; r1.w = a[7] * si + b8[7];
        float* op = out + (size_t)d * 256 + c * 32 + f * 8;
        __builtin_nontemporal_store(r0, (f32x4*)op);
        __builtin_nontemporal_store(r1, (f32x4*)(op + 4));
    }
}

extern "C" void kernel_launch(void* const* d_in, const int* in_sizes, int n_in,
                              void* d_out, int out_size, void* d_ws, size_t ws_size,
                              hipStream_t stream) {
    const float* feat = (const float*)d_in[0];
    const int*   src  = (const int*)d_in[1];
    const int*   dst  = (const int*)d_in[2];
    const float* W0   = (const float*)d_in[3];
    const float* b0   = (const float*)d_in[4];
    const float* W1   = (const float*)d_in[5];
    const float* b1   = (const float*)d_in[6];
    const float* W2   = (const float*)d_in[7];
    const float* b2   = (const float*)d_in[8];
    float* out = (float*)d_out;

    // ---- workspace bump allocator (64B aligned) ----
    char* p = (char*)d_ws;
    auto alloc = [&](size_t bytes) {
        char* r = p;
        p += (bytes + 63) & ~(size_t)63;
        return r;
    };
    float* outn = (float*)alloc(N_NODES * 4);
    float* inn  = (float*)alloc(N_NODES * 4);
    int* outc      = (int*)alloc(N_NODES * 4);     // | contiguous zero block:
    int* inc       = (int*)alloc(N_NODES * 4);     // | outc, inc, cursor, bcnt
    int* cursor    = (int*)alloc(N_NODES * 4);     // | (N_NODES*4 is 64B-mult)
    int* bcnt      = (int*)alloc(1024 * 4);        // |
    int* porder    = (int*)alloc(N_NODES * 4);
    int* base2     = (int*)alloc(N_NODES * 4);
    int* prow      = (int*)alloc((N_NODES + 1) * 4);
    int* bcur      = (int*)alloc(1024 * 4);
    int* n0        = (int*)alloc(1024 * 4);
    int* e0        = (int*)alloc(1024 * 4);
    int* csr2      = (int*)alloc(N_EDGES * 4);
    unsigned short* W0t = (unsigned short*)alloc(512 * 512 * 2);
    unsigned short* W1t = (unsigned short*)alloc(512 * 512 * 2);
    unsigned short* W2t = (unsigned short*)alloc(256 * 512 * 2);
    unsigned short* Af  = (unsigned short*)alloc((size_t)N_NODES * 512 * 2);
    unsigned short* H   = (unsigned short*)alloc((size_t)N_NODES * 512 * 2);

    const int NB = (N_NODES + 255) / 256;   // 196

    // ---- degrees + norms + closed-form degree sort + sorted CSR ----
    hipMemsetAsync(outc, 0, (size_t)3 * N_NODES * 4 + 1024 * 4, stream);
    hist_kernel<<<(N_EDGES + 255) / 256, 256, 0, stream>>>(src, dst, outc, inc);
    bucket_hist_norm<<<NB, 256, 0, stream>>>(inc, outc, bcnt, outn, inn);
    bucket_scan<<<1, 1024, 0, stream>>>(bcnt, bcur, n0, e0, prow);
    bucket_scatter<<<NB, 256, 0, stream>>>(inc, bcur, n0, e0, porder, prow, base2);
    fill_kernel<<<(N_EDGES + 255) / 256, 256, 0, stream>>>(src, dst, base2, cursor, csr2);

    // ---- weight transpose to fp16 (all 3 layers, one launch) ----
    conv_W3<<<dim3(16, 16, 3), 256, 0, stream>>>(W0, W1, W2, W0t, W1t, W2t);

    // ---- feature scale to fp16 ----
    long total4 = (long)N_NODES * 128;
    conv_A<<<(int)((total4 + 255) / 256), 256, 0, stream>>>(
        (const float4*)feat, outn, (ushort4*)Af, total4);

    dim3 g512((N_NODES + 127) / 128, 4);
    dim3 g256((N_NODES + 127) / 128, 2);
    dim3 gAgg512(8, NTB, 2);                // 16 chunks: one per block, 2 phases
    dim3 gAgg256(8, NTB);                   // 8 chunks: one per XCD

    // ---- layer 0 ----
    gemm_mfma<<<g512, 256, 0, stream>>>(Af, W0t, H, N_NODES, 512);
    agg_f16_v8<<<gAgg512, 256, 0, stream>>>(
        H, csr2, porder, prow, inn, outn, b0, Af);

    // ---- layer 1 ----
    gemm_mfma<<<g512, 256, 0, stream>>>(Af, W1t, H, N_NODES, 512);
    agg_f16_v8<<<gAgg512, 256, 0, stream>>>(
        H, csr2, porder, prow, inn, outn, b1, Af);

    // ---- layer 2 (256 out, no relu, fp32) ----
    gemm_mfma<<<g256, 256, 0, stream>>>(Af, W2t, H, N_NODES, 256);
    agg_f32_v8<<<gAgg256, 256, 0, stream>>>(
        H, csr2, porder, prow, inn, b2, out);
}